// Round 1
// baseline (434.885 us; speedup 1.0000x reference)
//
#include <hip/hip_runtime.h>

// Problem constants (from reference setup_inputs)
#define N_   32
#define T_   16
#define C_   128
#define H_   32
#define W_   32
#define CHW  (C_ * H_ * W_)      // 131072
#define CHW4 (CHW / 4)           // 32768 float4 per (n,t) slab

__global__ __launch_bounds__(256) void lif_kernel(
    const float4* __restrict__ x,      // (N, T, CHW/4)
    const float4* __restrict__ v_init, // (N, CHW/4)
    float4* __restrict__ out)          // (N, T, CHW/4)
{
    const int idx = blockIdx.x * blockDim.x + threadIdx.x;  // over N*CHW4
    const int n   = idx >> 15;          // idx / CHW4  (CHW4 = 2^15)
    const int rem = idx & (CHW4 - 1);   // idx % CHW4

    // base float4 index of (n, t=0, rem)
    const long long base = (long long)n * (T_ * CHW4) + rem;

    float4 v = v_init[idx];

    #pragma unroll
    for (int t = 0; t < T_; ++t) {
        const long long off = base + (long long)t * CHW4;
        float4 xt = x[off];
        float4 s;

        v.x = v.x * 0.5f + xt.x;  s.x = (v.x >= 1.0f) ? 1.0f : 0.0f;  v.x -= s.x;
        v.y = v.y * 0.5f + xt.y;  s.y = (v.y >= 1.0f) ? 1.0f : 0.0f;  v.y -= s.y;
        v.z = v.z * 0.5f + xt.z;  s.z = (v.z >= 1.0f) ? 1.0f : 0.0f;  v.z -= s.z;
        v.w = v.w * 0.5f + xt.w;  s.w = (v.w >= 1.0f) ? 1.0f : 0.0f;  v.w -= s.w;

        out[off] = s;
    }
}

extern "C" void kernel_launch(void* const* d_in, const int* in_sizes, int n_in,
                              void* d_out, int out_size, void* d_ws, size_t ws_size,
                              hipStream_t stream) {
    const float4* x  = (const float4*)d_in[0];   // (N,T,C,H,W) fp32
    const float4* v0 = (const float4*)d_in[1];   // (N,C,H,W)  fp32 zeros
    float4* out      = (float4*)d_out;           // (N,T,C,H,W) fp32

    const int total4 = N_ * CHW4;                // 1,048,576 threads
    const int block  = 256;
    const int grid   = total4 / block;           // 4096 blocks

    lif_kernel<<<grid, block, 0, stream>>>(x, v0, out);
}

// Round 3
// 422.367 us; speedup vs baseline: 1.0296x; 1.0296x over previous
//
#include <hip/hip_runtime.h>

// Problem constants (from reference setup_inputs)
#define N_   32
#define T_   16
#define C_   128
#define H_   32
#define W_   32
#define CHW  (C_ * H_ * W_)      // 131072
#define CHW4 (CHW / 4)           // 32768 float4 per (n,t) slab

// Native clang vector — required by __builtin_nontemporal_{load,store}
// (HIP_vector_type<float,4> is a struct and is rejected).
typedef float vf4 __attribute__((ext_vector_type(4)));

__global__ __launch_bounds__(256) void lif_kernel(
    const vf4* __restrict__ x,      // (N, T, CHW/4)
    const vf4* __restrict__ v_init, // (N, CHW/4)
    vf4* __restrict__ out)          // (N, T, CHW/4)
{
    const int idx = blockIdx.x * blockDim.x + threadIdx.x;  // over N*CHW4
    const int n   = idx >> 15;          // idx / CHW4  (CHW4 = 2^15)
    const int rem = idx & (CHW4 - 1);   // idx % CHW4

    // base vf4 index of (n, t=0, rem)
    const long long base = (long long)n * (T_ * CHW4) + rem;

    vf4 v = __builtin_nontemporal_load(&v_init[idx]);

    #pragma unroll
    for (int t = 0; t < T_; ++t) {
        const long long off = base + (long long)t * CHW4;
        // Zero-reuse streams: nontemporal hints keep x/out from thrashing
        // the LLC (which starts dirty with the harness's 0xAA poison fill).
        vf4 xt = __builtin_nontemporal_load(&x[off]);
        vf4 s;

        v.x = v.x * 0.5f + xt.x;  s.x = (v.x >= 1.0f) ? 1.0f : 0.0f;  v.x -= s.x;
        v.y = v.y * 0.5f + xt.y;  s.y = (v.y >= 1.0f) ? 1.0f : 0.0f;  v.y -= s.y;
        v.z = v.z * 0.5f + xt.z;  s.z = (v.z >= 1.0f) ? 1.0f : 0.0f;  v.z -= s.z;
        v.w = v.w * 0.5f + xt.w;  s.w = (v.w >= 1.0f) ? 1.0f : 0.0f;  v.w -= s.w;

        __builtin_nontemporal_store(s, &out[off]);
    }
}

extern "C" void kernel_launch(void* const* d_in, const int* in_sizes, int n_in,
                              void* d_out, int out_size, void* d_ws, size_t ws_size,
                              hipStream_t stream) {
    const vf4* x  = (const vf4*)d_in[0];   // (N,T,C,H,W) fp32
    const vf4* v0 = (const vf4*)d_in[1];   // (N,C,H,W)  fp32 zeros
    vf4* out      = (vf4*)d_out;           // (N,T,C,H,W) fp32

    const int total4 = N_ * CHW4;          // 1,048,576 threads
    const int block  = 256;
    const int grid   = total4 / block;     // 4096 blocks

    lif_kernel<<<grid, block, 0, stream>>>(x, v0, out);
}